// Round 5
// baseline (829.398 us; speedup 1.0000x reference)
//
#include <hip/hip_runtime.h>
#include <math.h>

namespace {

constexpr int kB = 4, kN = 512, kC = 256, kH = 8, kDG = 6, kHID = 16;

// LDS row strides (uints) chosen so lane-varying-h reads tile the 32 banks:
// stride mod 32 in {4,12,20,28} for b128 reads; 17 for b32 bias arrays.
constexpr int S_QH = 20;    // sQh row: 16 data + 4 pad
constexpr int S_W1 = 68;    // 16*4 + 4 pad
constexpr int S_W2 = 132;   // 16*8 + 4 pad
constexpr int S_B  = 17;    // 16 + 1 pad
constexpr int S_AT = 516;   // 512 + 4 pad

typedef _Float16 half2v __attribute__((ext_vector_type(2)));

__device__ __forceinline__ float swishf(float x) {
    return x * __builtin_amdgcn_rcpf(1.0f + __expf(-x));
}

__device__ __forceinline__ unsigned pk16(float a, float b) {
    unsigned short ha = __builtin_bit_cast(unsigned short, (_Float16)a);
    unsigned short hb = __builtin_bit_cast(unsigned short, (_Float16)b);
    return (unsigned)ha | ((unsigned)hb << 16);
}

__device__ __forceinline__ unsigned pkrtz(float a, float b) {
#if __has_builtin(__builtin_amdgcn_cvt_pkrtz)
    return __builtin_bit_cast(unsigned, __builtin_amdgcn_cvt_pkrtz(a, b));
#else
    return pk16(a, b);
#endif
}

__device__ __forceinline__ float fdot2u(unsigned a, unsigned b, float c) {
#if __has_builtin(__builtin_amdgcn_fdot2)
    return __builtin_amdgcn_fdot2(__builtin_bit_cast(half2v, a),
                                  __builtin_bit_cast(half2v, b), c, false);
#else
    half2v ha = __builtin_bit_cast(half2v, a);
    half2v hb = __builtin_bit_cast(half2v, b);
    return c + (float)ha[0] * (float)hb[0] + (float)ha[1] * (float)hb[1];
#endif
}

// QKV projection (blocks 0..255, 8 rows each) + mask decode/compaction
// (block 256). Q,K emitted as packed f16 (RTN); V stays f32.
__global__ __launch_bounds__(256) void k_qkvc(
    const float* __restrict__ x,
    const float* __restrict__ wq, const float* __restrict__ bq,
    const float* __restrict__ wk, const float* __restrict__ bk,
    const float* __restrict__ wv, const float* __restrict__ bv,
    unsigned* __restrict__ Qh, unsigned* __restrict__ Kh,
    float* __restrict__ V,
    const unsigned char* __restrict__ mraw,
    int* __restrict__ list, int* __restrict__ meta) {
    const int t = threadIdx.x;

    if (blockIdx.x == 256) {
        __shared__ int s_isbool;
        if (t == 0) s_isbool = 0;
        __syncthreads();
        int found = 0;
        for (int i = t; i < kB * kN; i += 256)
            if ((i & 3) && mraw[i]) found = 1;
        if (found) atomicOr(&s_isbool, 1);
        __syncthreads();
        const int isb = s_isbool;
        const int b = t >> 6, lane = t & 63;
        const int* mi = (const int*)mraw;
        int base = 0;
        for (int c = 0; c < 8; ++c) {
            const int m = c * 64 + lane;
            const int idx = b * kN + m;
            const int valid = isb ? (mraw[idx] != 0) : (mi[idx] != 0);
            unsigned long long bal = __ballot(valid);
            int rank = (int)__popcll(bal & ((1ull << lane) - 1ull));
            if (valid) list[b * kN + base + rank] = m;
            base += (int)__popcll(bal);
        }
        for (int i = base + lane; i < kN; i += 64)
            list[b * kN + i] = (base == 0) ? i : 0;
        if (lane == 0) {
            meta[b] = (base == 0) ? kN : base;
            meta[4 + b] = (base == 0);
        }
        return;
    }

    __shared__ float sx[8][kC];
    const int r0 = blockIdx.x * 8;
    #pragma unroll
    for (int r = 0; r < 8; ++r) sx[r][t] = x[(r0 + r) * kC + t];
    __syncthreads();
    float aq[8] = {}, ak[8] = {}, av[8] = {};
    for (int k = 0; k < kC; ++k) {
        const float q = wq[k * kC + t];
        const float kk = wk[k * kC + t];
        const float v = wv[k * kC + t];
        #pragma unroll
        for (int r = 0; r < 8; ++r) {
            aq[r] += sx[r][k] * q;
            ak[r] += sx[r][k] * kk;
            av[r] += sx[r][k] * v;
        }
    }
    const float qb = bq[t], kb = bk[t], vb = bv[t];
    #pragma unroll
    for (int r = 0; r < 8; ++r) {
        const float qv = aq[r] + qb;
        const float kv = ak[r] + kb;
        V[(r0 + r) * kC + t] = av[r] + vb;
        const float qn = __shfl_down(qv, 1);
        const float kn = __shfl_down(kv, 1);
        if ((t & 1) == 0) {
            Qh[(r0 + r) * (kC / 2) + (t >> 1)] = pk16(qv, qn);
            Kh[(r0 + r) * (kC / 2) + (t >> 1)] = pk16(kv, kn);
        }
    }
}

// Fused attention over the COMPACTED valid-m list. One block per (b,n).
// h = t&7 is loop-invariant per thread -> all weight bases hoisted.
// 2-way ILP: pairs (p0+pr, p0+pr+32) flow through the layers together so
// the two dependent chains interleave AND each LDS weight read feeds both.
// G read directly from global (block slice 12KB, L1-resident) -> LDS 27.3KB
// -> 5 blocks/CU at __launch_bounds__(256,5).
__global__ __launch_bounds__(256, 5) void k_attn(
    const float* __restrict__ G,
    const unsigned* __restrict__ Qh,
    const unsigned* __restrict__ Kh,
    const float* __restrict__ V,
    const float* __restrict__ w1, const float* __restrict__ b1,
    const float* __restrict__ w2, const float* __restrict__ b2,
    const float* __restrict__ w3, const float* __restrict__ b3,
    const int* __restrict__ list, const int* __restrict__ meta,
    float* __restrict__ out) {
    __shared__ __align__(16) unsigned sQh[kH * S_QH];    // 640 B
    __shared__ int sList[kN];                            // 2 KB
    __shared__ __align__(16) unsigned sW1[kH * S_W1];    // 2.2 KB
    __shared__ __align__(16) unsigned sW2[kH * S_W2];    // 4.2 KB
    __shared__ float sB1[kH * S_B];
    __shared__ float sB2[kH * S_B];
    __shared__ float sW3[kH * S_B];
    __shared__ float sB3[kH];
    __shared__ float sAtt[kH * S_AT];                    // 16.5 KB
    __shared__ float sInv[kH];

    const int bn = blockIdx.x;
    const int b = bn >> 9;
    const int t = threadIdx.x;

    // ---- staging ----
    if (t < kH * S_QH) {
        const int hh = t / S_QH, r = t % S_QH;
        sQh[t] = (r < 16) ? Qh[bn * (kC / 2) + hh * 16 + r] : 0u;
    }
    sList[t] = list[b * kN + t];
    sList[t + 256] = list[b * kN + t + 256];
    if (t < 128) {
        const int hh = t >> 4, k = t & 15;
        const float* wp = w1 + (hh * kDG) * kHID + k;  // w1[h][g][k], g-stride 16
        sW1[hh * S_W1 + k * 4 + 0] = pk16(wp[0], wp[16]);
        sW1[hh * S_W1 + k * 4 + 1] = pk16(wp[32], wp[48]);
        sW1[hh * S_W1 + k * 4 + 2] = pk16(wp[64], wp[80]);
        sW1[hh * S_W1 + k * 4 + 3] = 0;
        sB1[hh * S_B + k] = b1[hh * kHID + k];
        sB2[hh * S_B + k] = b2[hh * kHID + k];
        sW3[hh * S_B + k] = w3[hh * kHID + k];
    } else {
        const int t2 = t - 128;
        const int hh = t2 >> 4, j = t2 & 15;
        const float* wp = w2 + hh * kHID * kHID + j;   // w2[h][k][j], k-stride 16
        #pragma unroll
        for (int kp = 0; kp < 8; ++kp)
            sW2[hh * S_W2 + j * 8 + kp] = pk16(wp[(2 * kp) * kHID], wp[(2 * kp + 1) * kHID]);
        if (j == 0) sB3[hh] = b3[hh];
    }
    const int nv = meta[b];
    const int allm = meta[4 + b];
    __syncthreads();

    // ---- hoisted per-thread bases (h fixed) ----
    const int h = t & 7;
    const int pr = t >> 3;   // 0..31
    const unsigned* w1b = &sW1[h * S_W1];
    const unsigned* w2b = &sW2[h * S_W2];
    const float* b1b = &sB1[h * S_B];
    const float* b2b = &sB2[h * S_B];
    const float* w3b = &sW3[h * S_B];
    const float b3r = sB3[h];
    const uint4* qhb = (const uint4*)&sQh[h * S_QH];
    const unsigned* khbase = Kh + (size_t)(b * kN) * (kC / 2) + h * 16;
    const float* gbase = G + (size_t)bn * kN * kDG;
    float* attb = &sAtt[h * S_AT];

    #pragma unroll 1
    for (int p0 = 0; p0 < nv; p0 += 64) {
        const int pA = p0 + pr, pB = pA + 32;
        const int cA = min(pA, nv - 1), cB = min(pB, nv - 1);
        const int mA = sList[cA], mB = sList[cB];
        const float* gpA = gbase + (size_t)mA * kDG;
        const float* gpB = gbase + (size_t)mB * kDG;
        const uint4* khA = (const uint4*)(khbase + (size_t)mA * (kC / 2));
        const uint4* khB = (const uint4*)(khbase + (size_t)mB * (kC / 2));
        // A_feat
        float afA = 0.f, afB = 0.f;
        #pragma unroll
        for (int i = 0; i < 4; ++i) {
            const uint4 qv = qhb[i];
            const uint4 ka = khA[i];
            const uint4 kb2 = khB[i];
            afA = fdot2u(ka.x, qv.x, afA);
            afA = fdot2u(ka.y, qv.y, afA);
            afA = fdot2u(ka.z, qv.z, afA);
            afA = fdot2u(ka.w, qv.w, afA);
            afB = fdot2u(kb2.x, qv.x, afB);
            afB = fdot2u(kb2.y, qv.y, afB);
            afB = fdot2u(kb2.z, qv.z, afB);
            afB = fdot2u(kb2.w, qv.w, afB);
        }
        const unsigned gAx = pkrtz(gpA[0], gpA[1]);
        const unsigned gAy = pkrtz(gpA[2], gpA[3]);
        const unsigned gAz = pkrtz(gpA[4], gpA[5]);
        const unsigned gBx = pkrtz(gpB[0], gpB[1]);
        const unsigned gBy = pkrtz(gpB[2], gpB[3]);
        const unsigned gBz = pkrtz(gpB[4], gpB[5]);
        // layer 1: [6] -> [16]; each weight read feeds both items
        unsigned xpA[8], xpB[8];
        #pragma unroll
        for (int k2 = 0; k2 < 8; ++k2) {
            const uint4 wa = *(const uint4*)&w1b[8 * k2];
            const uint4 wb = *(const uint4*)&w1b[8 * k2 + 4];
            const float ba = b1b[2 * k2], bb = b1b[2 * k2 + 1];
            float aaA = ba, abA = bb, aaB = ba, abB = bb;
            aaA = fdot2u(gAx, wa.x, aaA);
            aaA = fdot2u(gAy, wa.y, aaA);
            aaA = fdot2u(gAz, wa.z, aaA);
            abA = fdot2u(gAx, wb.x, abA);
            abA = fdot2u(gAy, wb.y, abA);
            abA = fdot2u(gAz, wb.z, abA);
            aaB = fdot2u(gBx, wa.x, aaB);
            aaB = fdot2u(gBy, wa.y, aaB);
            aaB = fdot2u(gBz, wa.z, aaB);
            abB = fdot2u(gBx, wb.x, abB);
            abB = fdot2u(gBy, wb.y, abB);
            abB = fdot2u(gBz, wb.z, abB);
            xpA[k2] = pkrtz(swishf(aaA), swishf(abA));
            xpB[k2] = pkrtz(swishf(aaB), swishf(abB));
        }
        // layer 2 [16]->[16] + layer 3 [16]->1
        float a3A = b3r, a3B = b3r;
        #pragma unroll
        for (int j = 0; j < kHID; ++j) {
            const uint4 w0 = *(const uint4*)&w2b[j * 8];
            const uint4 w1q = *(const uint4*)&w2b[j * 8 + 4];
            const float bj = b2b[j];
            float accA = bj, accB = bj;
            accA = fdot2u(xpA[0], w0.x, accA);
            accA = fdot2u(xpA[1], w0.y, accA);
            accA = fdot2u(xpA[2], w0.z, accA);
            accA = fdot2u(xpA[3], w0.w, accA);
            accA = fdot2u(xpA[4], w1q.x, accA);
            accA = fdot2u(xpA[5], w1q.y, accA);
            accA = fdot2u(xpA[6], w1q.z, accA);
            accA = fdot2u(xpA[7], w1q.w, accA);
            accB = fdot2u(xpB[0], w0.x, accB);
            accB = fdot2u(xpB[1], w0.y, accB);
            accB = fdot2u(xpB[2], w0.z, accB);
            accB = fdot2u(xpB[3], w0.w, accB);
            accB = fdot2u(xpB[4], w1q.x, accB);
            accB = fdot2u(xpB[5], w1q.y, accB);
            accB = fdot2u(xpB[6], w1q.z, accB);
            accB = fdot2u(xpB[7], w1q.w, accB);
            const float wj = w3b[j];
            a3A += swishf(accA) * wj;
            a3B += swishf(accB) * wj;
        }
        const float valA = swishf(a3A) + afA * 0.0625f;
        const float valB = swishf(a3B) + afB * 0.0625f;
        if (pA < nv) attb[cA] = allm ? 0.f : valA;
        if (pB < nv) attb[cB] = allm ? 0.f : valB;
    }
    __syncthreads();

    // ---- per-head softmax over compacted range ----
    {
        const int hg = t >> 5;
        const int lane = t & 31;
        const int nv4 = (nv + 3) & ~3;
        float mx = -3.4e38f;
        for (int idx = lane; idx < nv; idx += 32)
            mx = fmaxf(mx, sAtt[hg * S_AT + idx]);
        #pragma unroll
        for (int off = 16; off; off >>= 1)
            mx = fmaxf(mx, __shfl_xor(mx, off));
        float ls = 0.f;
        for (int idx = lane; idx < nv4; idx += 32) {
            const float e = (idx < nv) ? __expf(sAtt[hg * S_AT + idx] - mx) : 0.f;
            sAtt[hg * S_AT + idx] = e;
            ls += e;
        }
        #pragma unroll
        for (int off = 16; off; off >>= 1)
            ls += __shfl_xor(ls, off);
        if (lane == 0) sInv[hg] = 1.0f / ls;
    }
    __syncthreads();

    // ---- att @ V over compacted list ----
    {
        const int hg = t >> 5;
        const int dd = t & 31;
        const int nv4 = (nv + 3) & ~3;
        const float* vb = V + (size_t)b * kN * kC + hg * 32 + dd;
        float a0 = 0.f, a1 = 0.f, a2 = 0.f, a3 = 0.f;
        for (int mc = 0; mc < nv4; mc += 4) {
            a0 += sAtt[hg * S_AT + mc + 0] * vb[(size_t)sList[mc + 0] * kC];
            a1 += sAtt[hg * S_AT + mc + 1] * vb[(size_t)sList[mc + 1] * kC];
            a2 += sAtt[hg * S_AT + mc + 2] * vb[(size_t)sList[mc + 2] * kC];
            a3 += sAtt[hg * S_AT + mc + 3] * vb[(size_t)sList[mc + 3] * kC];
        }
        out[bn * kC + t] = ((a0 + a1) + (a2 + a3)) * sInv[hg];
    }
}

// Final projection: out_pre @ out_w + out_b
__global__ __launch_bounds__(256) void k_proj(
    const float* __restrict__ x,
    const float* __restrict__ w, const float* __restrict__ bias,
    float* __restrict__ y) {
    __shared__ float sx[8][kC];
    const int r0 = blockIdx.x * 8;
    const int t = threadIdx.x;
    #pragma unroll
    for (int r = 0; r < 8; ++r) sx[r][t] = x[(r0 + r) * kC + t];
    __syncthreads();
    float acc[8] = {};
    for (int k = 0; k < kC; ++k) {
        const float wv = w[k * kC + t];
        #pragma unroll
        for (int r = 0; r < 8; ++r) acc[r] += sx[r][k] * wv;
    }
    const float bb = bias[t];
    #pragma unroll
    for (int r = 0; r < 8; ++r) y[(r0 + r) * kC + t] = acc[r] + bb;
}

}  // namespace

extern "C" void kernel_launch(void* const* d_in, const int* in_sizes, int n_in,
                              void* d_out, int out_size, void* d_ws, size_t ws_size,
                              hipStream_t stream) {
    (void)in_sizes; (void)n_in; (void)out_size; (void)ws_size;
    const float* G  = (const float*)d_in[0];
    const float* cf = (const float*)d_in[1];
    const float* wq = (const float*)d_in[2];
    const float* bq = (const float*)d_in[3];
    const float* wk = (const float*)d_in[4];
    const float* bk = (const float*)d_in[5];
    const float* wv = (const float*)d_in[6];   // in_w
    const float* bv = (const float*)d_in[7];   // in_b
    const float* wo = (const float*)d_in[8];   // out_w
    const float* bo = (const float*)d_in[9];   // out_b
    const float* w1 = (const float*)d_in[10];
    const float* b1 = (const float*)d_in[11];
    const float* w2 = (const float*)d_in[12];
    const float* b2 = (const float*)d_in[13];
    const float* w3 = (const float*)d_in[14];
    const float* b3 = (const float*)d_in[15];
    const unsigned char* mraw = (const unsigned char*)d_in[16];

    const int rows = kB * kN;  // 2048
    unsigned* Qh = (unsigned*)d_ws;                     // 1 MB
    unsigned* Kh = Qh + (size_t)rows * (kC / 2);        // 1 MB
    float* V = (float*)(Kh + (size_t)rows * (kC / 2));  // 2 MB
    float* O = V + (size_t)rows * kC;                   // 2 MB
    int* list = (int*)(O + (size_t)rows * kC);          // 8 KB
    int* meta = list + rows;                            // 32 B

    k_qkvc<<<257, 256, 0, stream>>>(cf, wq, bq, wk, bk, wv, bv,
                                    Qh, Kh, V, mraw, list, meta);
    k_attn<<<rows, 256, 0, stream>>>(G, Qh, Kh, V, w1, b1, w2, b2, w3, b3,
                                     list, meta, O);
    k_proj<<<rows / 8, 256, 0, stream>>>(O, wo, bo, (float*)d_out);
}

// Round 7
// 264.133 us; speedup vs baseline: 3.1401x; 3.1401x over previous
//
#include <hip/hip_runtime.h>
#include <math.h>

namespace {

constexpr int kB = 4, kN = 512, kC = 256, kH = 8, kDG = 6, kHID = 16;

// LDS strides (uints/floats). b128 reads at h*20+s*4 are 16B-aligned and
// tile banks; sAtt stride 516 => h-groups land on distinct banks.
constexpr int S_QH = 20;
constexpr int S_BT = 20;
constexpr int S_AT = 516;

typedef _Float16 half2v __attribute__((ext_vector_type(2)));
typedef _Float16 half4v __attribute__((ext_vector_type(4)));
typedef float float4v __attribute__((ext_vector_type(4)));
typedef unsigned uint2v __attribute__((ext_vector_type(2)));

__device__ __forceinline__ float swishf(float x) {
    return x * __builtin_amdgcn_rcpf(1.0f + __expf(-x));
}

__device__ __forceinline__ unsigned pk16(float a, float b) {
    unsigned short ha = __builtin_bit_cast(unsigned short, (_Float16)a);
    unsigned short hb = __builtin_bit_cast(unsigned short, (_Float16)b);
    return (unsigned)ha | ((unsigned)hb << 16);
}

__device__ __forceinline__ unsigned pkrtz(float a, float b) {
    return __builtin_bit_cast(unsigned, __builtin_amdgcn_cvt_pkrtz(a, b));
}

__device__ __forceinline__ float4v mfma16(half4v a, half4v b, float4v c) {
    return __builtin_amdgcn_mfma_f32_16x16x16f16(a, b, c, 0, 0, 0);
}

// QKV projection (blocks 0..255, 8 rows each) + mask decode/compaction
// (block 256). Q,K,V all emitted as packed f16 pairs.
__global__ __launch_bounds__(256) void k_qkvc(
    const float* __restrict__ x,
    const float* __restrict__ wq, const float* __restrict__ bq,
    const float* __restrict__ wk, const float* __restrict__ bk,
    const float* __restrict__ wv, const float* __restrict__ bv,
    unsigned* __restrict__ Qh, unsigned* __restrict__ Kh,
    unsigned* __restrict__ Vh,
    const unsigned char* __restrict__ mraw,
    int* __restrict__ list, int* __restrict__ meta) {
    const int t = threadIdx.x;

    if (blockIdx.x == 256) {
        __shared__ int s_isbool;
        if (t == 0) s_isbool = 0;
        __syncthreads();
        int found = 0;
        for (int i = t; i < kB * kN; i += 256)
            if ((i & 3) && mraw[i]) found = 1;
        if (found) atomicOr(&s_isbool, 1);
        __syncthreads();
        const int isb = s_isbool;
        const int b = t >> 6, lane = t & 63;
        const int* mi = (const int*)mraw;
        int base = 0;
        for (int c = 0; c < 8; ++c) {
            const int m = c * 64 + lane;
            const int idx = b * kN + m;
            const int valid = isb ? (mraw[idx] != 0) : (mi[idx] != 0);
            unsigned long long bal = __ballot(valid);
            int rank = (int)__popcll(bal & ((1ull << lane) - 1ull));
            if (valid) list[b * kN + base + rank] = m;
            base += (int)__popcll(bal);
        }
        for (int i = base + lane; i < kN; i += 64)
            list[b * kN + i] = (base == 0) ? i : 0;
        if (lane == 0) {
            meta[b] = (base == 0) ? kN : base;
            meta[4 + b] = (base == 0);
        }
        return;
    }

    __shared__ float sx[8][kC];
    const int r0 = blockIdx.x * 8;
    #pragma unroll
    for (int r = 0; r < 8; ++r) sx[r][t] = x[(r0 + r) * kC + t];
    __syncthreads();
    float aq[8] = {}, ak[8] = {}, av[8] = {};
    for (int k = 0; k < kC; ++k) {
        const float q = wq[k * kC + t];
        const float kk = wk[k * kC + t];
        const float v = wv[k * kC + t];
        #pragma unroll
        for (int r = 0; r < 8; ++r) {
            aq[r] += sx[r][k] * q;
            ak[r] += sx[r][k] * kk;
            av[r] += sx[r][k] * v;
        }
    }
    const float qb = bq[t], kb = bk[t], vb = bv[t];
    #pragma unroll
    for (int r = 0; r < 8; ++r) {
        const float qv = aq[r] + qb;
        const float kv = ak[r] + kb;
        const float vv = av[r] + vb;
        const float qn = __shfl_down(qv, 1);
        const float kn = __shfl_down(kv, 1);
        const float vn = __shfl_down(vv, 1);
        if ((t & 1) == 0) {
            Qh[(r0 + r) * (kC / 2) + (t >> 1)] = pk16(qv, qn);
            Kh[(r0 + r) * (kC / 2) + (t >> 1)] = pk16(kv, kn);
            Vh[(r0 + r) * (kC / 2) + (t >> 1)] = pk16(vv, vn);
        }
    }
}

// Fused attention, MFMA-based MLP over the compacted list. One block/(b,n).
// Transposed-operand scheme: Z^T = W^T @ X^T with v_mfma_f32_16x16x16f16.
//   A (lane): row=l%16, k=4*(l/16)+r  -> W^T fragments held in VGPRs.
//   B (lane): col=l%16, k=4*(l/16)+r  -> 4 input features of pair p=l%16.
//   C (lane): col=l%16, row=4*(l/16)+r-> 4 output features of pair p
//     == next layer's B after swish+pkrtz, entirely in-lane.
// Layer3 and QK^T use broadcast-A (all rows equal) so C[0] is the scalar
// result -- no cross-lane reduction anywhere in the MLP.
__global__ __launch_bounds__(256, 4) void k_attn(
    const float* __restrict__ G,
    const unsigned* __restrict__ Qh,
    const unsigned* __restrict__ Kh,
    const unsigned* __restrict__ Vh,
    const float* __restrict__ w1, const float* __restrict__ b1,
    const float* __restrict__ w2, const float* __restrict__ b2,
    const float* __restrict__ w3, const float* __restrict__ b3,
    const int* __restrict__ list, const int* __restrict__ meta,
    float* __restrict__ out) {
    __shared__ __align__(16) unsigned sQh[kH * S_QH];   // 640 B
    __shared__ __align__(16) uint4 sG4[kN];             // 8 KB packed f16 g
    __shared__ int sList[kN];                           // 2 KB
    __shared__ __align__(16) float sB1T[kH * S_BT];     // 640 B
    __shared__ __align__(16) float sB2T[kH * S_BT];
    __shared__ __align__(16) float sW3T[kH * S_BT];
    __shared__ float sB3[kH];
    __shared__ float sAtt[kH * S_AT];                   // 16.5 KB
    __shared__ float sInv[kH];

    const int bn = blockIdx.x;
    const int b = bn >> 9;
    const int t = threadIdx.x;
    const int l = t & 63;
    const int p = l & 15;        // pair-in-tile (mfma col)
    const int s = l >> 4;        // k-slice (mfma k-quarter)
    const int wid = t >> 6;      // wave 0..3

    // ---- A fragments: W1^T, W2^T in registers (prologue, L2-hot) ----
    half4v a1f[kH], a2f[kH];
    #pragma unroll
    for (int h = 0; h < kH; ++h) {
        #pragma unroll
        for (int r = 0; r < 4; ++r) {
            const int k = 4 * s + r;
            a1f[h][r] = (k < kDG) ? (_Float16)w1[(h * kDG + k) * kHID + p]
                                  : (_Float16)0.f;
            a2f[h][r] = (_Float16)w2[(h * kHID + k) * kHID + p];
        }
    }

    // ---- staging ----
    if (t < kH * S_QH) {
        const int hh = t / S_QH, r = t % S_QH;
        sQh[t] = (r < 16) ? Qh[bn * (kC / 2) + hh * 16 + r] : 0u;
    }
    sList[t] = list[b * kN + t];
    sList[t + 256] = list[b * kN + t + 256];
    #pragma unroll 1
    for (int rep = 0; rep < 2; ++rep) {
        const int m = t + rep * 256;
        const float* gp = G + ((size_t)bn * kN + m) * kDG;
        uint4 gw;
        gw.x = pkrtz(gp[0], gp[1]);
        gw.y = pkrtz(gp[2], gp[3]);
        gw.z = pkrtz(gp[4], gp[5]);
        gw.w = 0;
        sG4[m] = gw;
    }
    if (t < 128) {
        const int hh = t >> 4, j = t & 15;
        sB1T[hh * S_BT + j] = b1[hh * kHID + j];
        sB2T[hh * S_BT + j] = b2[hh * kHID + j];
        sW3T[hh * S_BT + j] = w3[hh * kHID + j];
        if (j == 0) sB3[hh] = b3[hh];
    }
    const int nv = meta[b];
    const int allm = meta[4 + b];
    __syncthreads();

    const unsigned* khB = Kh + (size_t)(b * kN) * (kC / 2);
    const int ntiles = (nv + 15) >> 4;

    // ---- per-head MLP + QK^T (h unrolled so a1f/a2f stay registers) ----
    #pragma unroll
    for (int h = 0; h < kH; ++h) {
        const float4v bv1 = *(const float4v*)&sB1T[h * S_BT + s * 4];
        const float4v bv2 = *(const float4v*)&sB2T[h * S_BT + s * 4];
        const float4v w3f = *(const float4v*)&sW3T[h * S_BT + s * 4];
        half4v w3h;
        #pragma unroll
        for (int r = 0; r < 4; ++r) w3h[r] = (_Float16)w3f[r];
        const float b3s = sB3[h];
        const float4v b3v = {b3s, b3s, b3s, b3s};
        // Q broadcast-A fragments (d halves 0/1)
        const uint2v q0u = {sQh[h * S_QH + 2 * s], sQh[h * S_QH + 2 * s + 1]};
        const uint2v q1u = {sQh[h * S_QH + 8 + 2 * s], sQh[h * S_QH + 9 + 2 * s]};
        const half4v qA0 = __builtin_bit_cast(half4v, q0u);
        const half4v qA1 = __builtin_bit_cast(half4v, q1u);

        #pragma unroll 1
        for (int tile = wid; tile < ntiles; tile += 4) {
            const int mcw = tile * 16 + p;
            const int mc = min(mcw, nv - 1);
            const int m = sList[mc];
            // B1: g fragment (k=4s+r -> g[k] or 0)
            const unsigned* gp = (const unsigned*)&sG4[m];
            uint2v gu = {gp[(s & 1) * 2], gp[(s & 1) * 2 + 1]};
            if (s >= 2) { gu[0] = 0u; gu[1] = 0u; }
            const half4v bg = __builtin_bit_cast(half4v, gu);
            // layer 1 (bias as C-in)
            const float4v c1 = mfma16(a1f[h], bg, bv1);
            const uint2v x1u = {pkrtz(swishf(c1[0]), swishf(c1[1])),
                                pkrtz(swishf(c1[2]), swishf(c1[3]))};
            // layer 2
            const float4v c2 = mfma16(a2f[h], __builtin_bit_cast(half4v, x1u), bv2);
            const uint2v x2u = {pkrtz(swishf(c2[0]), swishf(c2[1])),
                                pkrtz(swishf(c2[2]), swishf(c2[3]))};
            // layer 3: broadcast-A w3 -> every C row holds a3
            const float4v c3 = mfma16(w3h, __builtin_bit_cast(half4v, x2u), b3v);
            // A_feat: broadcast-A Q, B = K^T (two K=16 halves chained)
            const unsigned* kr = khB + (size_t)m * (kC / 2) + h * 16 + 2 * s;
            const uint2v k0 = {kr[0], kr[1]};
            const uint2v k1 = {kr[8], kr[9]};
            float4v ca = {0.f, 0.f, 0.f, 0.f};
            ca = mfma16(qA0, __builtin_bit_cast(half4v, k0), ca);
            ca = mfma16(qA1, __builtin_bit_cast(half4v, k1), ca);
            const float pre = swishf(c3[0]) + ca[0] * 0.0625f;
            if (s == 0 && mcw < nv)
                sAtt[h * S_AT + mcw] = allm ? 0.f : pre;
        }
    }
    __syncthreads();

    // ---- per-head softmax over compacted range ----
    {
        const int hg = t >> 5;
        const int lane = t & 31;
        float mx = -3.4e38f;
        for (int idx = lane; idx < nv; idx += 32)
            mx = fmaxf(mx, sAtt[hg * S_AT + idx]);
        #pragma unroll
        for (int off = 16; off; off >>= 1)
            mx = fmaxf(mx, __shfl_xor(mx, off));
        float ls = 0.f;
        for (int idx = lane; idx < nv; idx += 32) {
            const float e = __expf(sAtt[hg * S_AT + idx] - mx);
            sAtt[hg * S_AT + idx] = e;
            ls += e;
        }
        #pragma unroll
        for (int off = 16; off; off >>= 1)
            ls += __shfl_xor(ls, off);
        if (lane == 0) sInv[hg] = 1.0f / ls;
    }
    __syncthreads();

    // ---- att @ V (V packed f16; thread = (head, d-pair, parity)) ----
    {
        const int hg = t >> 5;
        const int dp = (t >> 1) & 15;
        const int par = t & 1;
        const unsigned* vbp = Vh + (size_t)(b * kN) * (kC / 2) + hg * 16 + dp;
        float alo = 0.f, ahi = 0.f, blo = 0.f, bhi = 0.f;
        int mc = par;
        for (; mc + 2 < nv; mc += 4) {
            const float aw0 = sAtt[hg * S_AT + mc];
            const float aw1 = sAtt[hg * S_AT + mc + 2];
            const half2v v0 = __builtin_bit_cast(half2v, vbp[(size_t)sList[mc] * (kC / 2)]);
            const half2v v1 = __builtin_bit_cast(half2v, vbp[(size_t)sList[mc + 2] * (kC / 2)]);
            alo += aw0 * (float)v0[0];
            ahi += aw0 * (float)v0[1];
            blo += aw1 * (float)v1[0];
            bhi += aw1 * (float)v1[1];
        }
        for (; mc < nv; mc += 2) {
            const float aw = sAtt[hg * S_AT + mc];
            const half2v vv = __builtin_bit_cast(half2v, vbp[(size_t)sList[mc] * (kC / 2)]);
            alo += aw * (float)vv[0];
            ahi += aw * (float)vv[1];
        }
        alo += blo; ahi += bhi;
        alo += __shfl_xor(alo, 1);   // combine the two parities
        ahi += __shfl_xor(ahi, 1);
        out[bn * kC + t] = (par ? ahi : alo) * sInv[hg];
    }
}

// Final projection: out_pre @ out_w + out_b
__global__ __launch_bounds__(256) void k_proj(
    const float* __restrict__ x,
    const float* __restrict__ w, const float* __restrict__ bias,
    float* __restrict__ y) {
    __shared__ float sx[8][kC];
    const int r0 = blockIdx.x * 8;
    const int t = threadIdx.x;
    #pragma unroll
    for (int r = 0; r < 8; ++r) sx[r][t] = x[(r0 + r) * kC + t];
    __syncthreads();
    float acc[8] = {};
    for (int k = 0; k < kC; ++k) {
        const float wv = w[k * kC + t];
        #pragma unroll
        for (int r = 0; r < 8; ++r) acc[r] += sx[r][k] * wv;
    }
    const float bb = bias[t];
    #pragma unroll
    for (int r = 0; r < 8; ++r) y[(r0 + r) * kC + t] = acc[r] + bb;
}

}  // namespace

extern "C" void kernel_launch(void* const* d_in, const int* in_sizes, int n_in,
                              void* d_out, int out_size, void* d_ws, size_t ws_size,
                              hipStream_t stream) {
    (void)in_sizes; (void)n_in; (void)out_size; (void)ws_size;
    const float* G  = (const float*)d_in[0];
    const float* cf = (const float*)d_in[1];
    const float* wq = (const float*)d_in[2];
    const float* bq = (const float*)d_in[3];
    const float* wk = (const float*)d_in[4];
    const float* bk = (const float*)d_in[5];
    const float* wv = (const float*)d_in[6];   // in_w
    const float* bv = (const float*)d_in[7];   // in_b
    const float* wo = (const float*)d_in[8];   // out_w
    const float* bo = (const float*)d_in[9];   // out_b
    const float* w1 = (const float*)d_in[10];
    const float* b1 = (const float*)d_in[11];
    const float* w2 = (const float*)d_in[12];
    const float* b2 = (const float*)d_in[13];
    const float* w3 = (const float*)d_in[14];
    const float* b3 = (const float*)d_in[15];
    const unsigned char* mraw = (const unsigned char*)d_in[16];

    const int rows = kB * kN;  // 2048
    unsigned* Qh = (unsigned*)d_ws;                       // 1 MB
    unsigned* Kh = Qh + (size_t)rows * (kC / 2);          // 1 MB
    unsigned* Vh = Kh + (size_t)rows * (kC / 2);          // 1 MB
    float* O = (float*)(Vh + (size_t)rows * (kC / 2));    // 2 MB
    int* list = (int*)(O + (size_t)rows * kC);            // 8 KB
    int* meta = list + rows;                              // 32 B

    k_qkvc<<<257, 256, 0, stream>>>(cf, wq, bq, wk, bk, wv, bv,
                                    Qh, Kh, Vh, mraw, list, meta);
    k_attn<<<rows, 256, 0, stream>>>(G, Qh, Kh, Vh, w1, b1, w2, b2, w3, b3,
                                     list, meta, O);
    k_proj<<<rows / 8, 256, 0, stream>>>(O, wo, bo, (float*)d_out);
}